// Round 1
// baseline (1365.667 us; speedup 1.0000x reference)
//
#include <hip/hip_runtime.h>

#define LN_EPS 1e-5f
#define D 128

// K0: Wt[half][k][j] = W[j][k]  (half 0 = W_l, 1 = W_r), so the GEMM's
// j-loop reads consecutive, wave-uniform addresses.
__global__ void prep_w(const float* __restrict__ Wl,
                       const float* __restrict__ Wr,
                       float* __restrict__ Wt) {
    int idx = blockIdx.x * blockDim.x + threadIdx.x;
    if (idx >= 2 * D * D) return;
    int half = idx / (D * D);
    int k = (idx / D) % D;
    int j = idx % D;
    const float* W = half ? Wr : Wl;
    Wt[idx] = W[j * D + k];
}

// K1: LayerNorm + ReLU + dropout-mask. One 64-lane wave per node,
// float2 per lane (coalesced 512B row read), shuffle reduction.
__global__ void ln_relu_drop(const float* __restrict__ x,
                             const float* __restrict__ mask,
                             const float* __restrict__ gamma,
                             const float* __restrict__ beta,
                             float* __restrict__ h, int N) {
    int node = (blockIdx.x * blockDim.x + threadIdx.x) >> 6;
    int lane = threadIdx.x & 63;
    if (node >= N) return;
    float2 v = ((const float2*)(x + (size_t)node * D))[lane];
    float s  = v.x + v.y;
    float ss = v.x * v.x + v.y * v.y;
#pragma unroll
    for (int off = 32; off > 0; off >>= 1) {
        s  += __shfl_xor(s, off);
        ss += __shfl_xor(ss, off);
    }
    float mu  = s * (1.0f / D);
    float var = ss * (1.0f / D) - mu * mu;
    float rs  = rsqrtf(var + LN_EPS);
    float2 g = ((const float2*)gamma)[lane];
    float2 b = ((const float2*)beta)[lane];
    float2 m = ((const float2*)(mask + (size_t)node * D))[lane];
    float2 o;
    o.x = fmaxf((v.x - mu) * rs * g.x + b.x, 0.0f) * m.x;
    o.y = fmaxf((v.y - mu) * rs * g.y + b.y, 0.0f) * m.y;
    ((float2*)(h + (size_t)node * D))[lane] = o;
}

// K3: edge scatter. 32 threads per edge, float4 per thread,
// native fp32 atomics into agg[dst]; lane 0 bumps the count.
__global__ void scatter_add(const float* __restrict__ h,
                            const int* __restrict__ ei,
                            float* __restrict__ agg,
                            float* __restrict__ cnt,
                            int E) {
    int gid = blockIdx.x * blockDim.x + threadIdx.x;
    int e = gid >> 5;
    if (e >= E) return;
    int c = gid & 31;
    int src = ei[e];
    int dst = ei[E + e];
    float4 v = ((const float4*)(h + (size_t)src * D))[c];
    float* a = agg + (size_t)dst * D + c * 4;
    unsafeAtomicAdd(a + 0, v.x);
    unsafeAtomicAdd(a + 1, v.y);
    unsafeAtomicAdd(a + 2, v.z);
    unsafeAtomicAdd(a + 3, v.w);
    if (c == 0) unsafeAtomicAdd(&cnt[dst], 1.0f);
}

// K4: out[n] = (agg[n]/max(cnt,1)) @ Wl^T + b + h[n] @ Wr^T.
// One thread per node; acc[128] lives in VGPRs; Wt rows are wave-uniform
// so the j-loop loads broadcast (one L1/L2 load serves 64 nodes).
// In-place on h: row n is fully read before it is written.
__global__ void __launch_bounds__(256, 2)
out_gemm(float* __restrict__ hout,
         const float* __restrict__ agg,
         const float* __restrict__ cnt,
         const float* __restrict__ Wt,
         const float* __restrict__ bl,
         int N) {
    int n = blockIdx.x * blockDim.x + threadIdx.x;
    if (n >= N) return;
    float acc[D];
#pragma unroll
    for (int j = 0; j < D; j++) acc[j] = 0.0f;
    float invc = 1.0f / fmaxf(cnt[n], 1.0f);
    const float* arow = agg  + (size_t)n * D;
    const float* hrow = hout + (size_t)n * D;
    for (int k = 0; k < D; k++) {
        float a = arow[k] * invc;
        const float* w = Wt + k * D;
#pragma unroll
        for (int j = 0; j < D; j++) acc[j] = fmaf(a, w[j], acc[j]);
    }
    for (int k = 0; k < D; k++) {
        float a = hrow[k];
        const float* w = Wt + (D + k) * D;
#pragma unroll
        for (int j = 0; j < D; j++) acc[j] = fmaf(a, w[j], acc[j]);
    }
    float* orow = hout + (size_t)n * D;
#pragma unroll
    for (int j = 0; j < D; j++) orow[j] = acc[j] + bl[j];
}

extern "C" void kernel_launch(void* const* d_in, const int* in_sizes, int n_in,
                              void* d_out, int out_size, void* d_ws, size_t ws_size,
                              hipStream_t stream) {
    const float* x     = (const float*)d_in[0];
    const int*   ei    = (const int*)  d_in[1];
    const float* mask  = (const float*)d_in[2];
    const float* gamma = (const float*)d_in[3];
    const float* beta  = (const float*)d_in[4];
    const float* Wl    = (const float*)d_in[5];
    const float* bl    = (const float*)d_in[6];
    const float* Wr    = (const float*)d_in[7];
    float* out = (float*)d_out;

    int N = in_sizes[0] / D;   // 100000
    int E = in_sizes[1] / 2;   // 600000

    // ws layout: agg[N*D] | cnt[N] | Wt[2*D*D]
    float* agg = (float*)d_ws;
    float* cnt = agg + (size_t)N * D;
    float* Wt  = cnt + N;

    hipMemsetAsync(d_ws, 0, ((size_t)N * D + N) * sizeof(float), stream);
    prep_w<<<(2 * D * D + 255) / 256, 256, 0, stream>>>(Wl, Wr, Wt);
    ln_relu_drop<<<(N + 3) / 4, 256, 0, stream>>>(x, mask, gamma, beta, out, N);
    int scatter_blocks = (int)(((size_t)E * 32 + 255) / 256);
    scatter_add<<<scatter_blocks, 256, 0, stream>>>(out, ei, agg, cnt, E);
    out_gemm<<<(N + 255) / 256, 256, 0, stream>>>(out, agg, cnt, Wt, bl, N);
}

// Round 2
// 466.315 us; speedup vs baseline: 2.9286x; 2.9286x over previous
//
#include <hip/hip_runtime.h>

#define LN_EPS 1e-5f
#define D 128
#define SCAN_CHUNK 1024

// K0: Wt[half][k][j] = W[j][k]  (half 0 = W_l, 1 = W_r) so the GEMM's
// j-loop reads consecutive, wave-uniform addresses.
__global__ void prep_w(const float* __restrict__ Wl,
                       const float* __restrict__ Wr,
                       float* __restrict__ Wt) {
    int idx = blockIdx.x * blockDim.x + threadIdx.x;
    if (idx >= 2 * D * D) return;
    int half = idx / (D * D);
    int k = (idx / D) % D;
    int j = idx % D;
    const float* W = half ? Wr : Wl;
    Wt[idx] = W[j * D + k];
}

// K1: LayerNorm + ReLU + dropout-mask. One 64-lane wave per node.
__global__ void ln_relu_drop(const float* __restrict__ x,
                             const float* __restrict__ mask,
                             const float* __restrict__ gamma,
                             const float* __restrict__ beta,
                             float* __restrict__ h, int N) {
    int node = (blockIdx.x * blockDim.x + threadIdx.x) >> 6;
    int lane = threadIdx.x & 63;
    if (node >= N) return;
    float2 v = ((const float2*)(x + (size_t)node * D))[lane];
    float s  = v.x + v.y;
    float ss = v.x * v.x + v.y * v.y;
#pragma unroll
    for (int off = 32; off > 0; off >>= 1) {
        s  += __shfl_xor(s, off);
        ss += __shfl_xor(ss, off);
    }
    float mu  = s * (1.0f / D);
    float var = ss * (1.0f / D) - mu * mu;
    float rs  = rsqrtf(var + LN_EPS);
    float2 g = ((const float2*)gamma)[lane];
    float2 b = ((const float2*)beta)[lane];
    float2 m = ((const float2*)(mask + (size_t)node * D))[lane];
    float2 o;
    o.x = fmaxf((v.x - mu) * rs * g.x + b.x, 0.0f) * m.x;
    o.y = fmaxf((v.y - mu) * rs * g.y + b.y, 0.0f) * m.y;
    ((float2*)(h + (size_t)node * D))[lane] = o;
}

// K2: degree histogram over dst (int atomics).
__global__ void hist_k(const int* __restrict__ ei, int* __restrict__ hist, int E) {
    int e = blockIdx.x * blockDim.x + threadIdx.x;
    if (e >= E) return;
    atomicAdd(&hist[ei[E + e]], 1);
}

// K3a: per-chunk exclusive scan (1024 elems / block of 256 threads).
__global__ void scan1(const int* __restrict__ hist, int* __restrict__ offs,
                      int* __restrict__ chunk_sums, int N) {
    __shared__ int lds[256];
    int base = blockIdx.x * SCAN_CHUNK;
    int t = threadIdx.x;
    int idx0 = base + t * 4;
    int v[4];
#pragma unroll
    for (int i = 0; i < 4; i++) {
        int idx = idx0 + i;
        v[i] = (idx < N) ? hist[idx] : 0;
    }
    lds[t] = v[0] + v[1] + v[2] + v[3];
    __syncthreads();
    for (int off = 1; off < 256; off <<= 1) {
        int add = (t >= off) ? lds[t - off] : 0;
        __syncthreads();
        lds[t] += add;
        __syncthreads();
    }
    int run = (t == 0) ? 0 : lds[t - 1];
    if (t == 255) chunk_sums[blockIdx.x] = lds[255];
#pragma unroll
    for (int i = 0; i < 4; i++) {
        int idx = idx0 + i;
        if (idx < N) offs[idx] = run;
        run += v[i];
    }
}

// K3b: single-block exclusive scan of the chunk sums (C <= 128).
__global__ void scan2(int* __restrict__ chunk_sums, int C) {
    __shared__ int lds[128];
    int t = threadIdx.x;
    lds[t] = (t < C) ? chunk_sums[t] : 0;
    __syncthreads();
    for (int off = 1; off < 128; off <<= 1) {
        int add = (t >= off) ? lds[t - off] : 0;
        __syncthreads();
        lds[t] += add;
        __syncthreads();
    }
    int excl = (t == 0) ? 0 : lds[t - 1];
    if (t < C) chunk_sums[t] = excl;
}

// K3c: add chunk bases; also init the scatter cursor.
__global__ void scan3(int* __restrict__ offs, const int* __restrict__ chunk_sums,
                      int* __restrict__ cursor, int N) {
    int i = blockIdx.x * blockDim.x + threadIdx.x;
    if (i >= N) return;
    int v = offs[i] + chunk_sums[i / SCAN_CHUNK];
    offs[i] = v;
    cursor[i] = v;
}

// K4: bucket edges by dst (counting-sort placement; int atomics only).
__global__ void sort_edges(const int* __restrict__ ei, int* __restrict__ cursor,
                           int* __restrict__ sorted_src, int E) {
    int e = blockIdx.x * blockDim.x + threadIdx.x;
    if (e >= E) return;
    int dst = ei[E + e];
    int pos = atomicAdd(&cursor[dst], 1);
    sorted_src[pos] = ei[e];
}

// K5: segmented mean-aggregate. One wave per node; each edge's h-row is a
// coalesced 512B read (float2/lane), accumulate in registers, single write.
__global__ void aggregate(const float* __restrict__ h,
                          const int* __restrict__ sorted_src,
                          const int* __restrict__ offs,
                          const int* __restrict__ hist,
                          float* __restrict__ mean_agg, int N) {
    int node = (blockIdx.x * blockDim.x + threadIdx.x) >> 6;
    int lane = threadIdx.x & 63;
    if (node >= N) return;
    int start = offs[node];
    int deg = hist[node];
    float ax = 0.0f, ay = 0.0f;
    for (int i = 0; i < deg; i++) {
        int src = sorted_src[start + i];
        float2 v = ((const float2*)(h + (size_t)src * D))[lane];
        ax += v.x; ay += v.y;
    }
    float inv = 1.0f / fmaxf((float)deg, 1.0f);
    float2 o; o.x = ax * inv; o.y = ay * inv;
    ((float2*)(mean_agg + (size_t)node * D))[lane] = o;
}

// K6: out[n] = mean_agg[n] @ Wl^T + b + h[n] @ Wr^T.
// One thread per node; acc[128] in VGPRs; Wt rows wave-uniform (broadcast).
__global__ void __launch_bounds__(256, 2)
out_gemm(float* __restrict__ hout,
         const float* __restrict__ magg,
         const float* __restrict__ Wt,
         const float* __restrict__ bl,
         int N) {
    int n = blockIdx.x * blockDim.x + threadIdx.x;
    if (n >= N) return;
    float acc[D];
#pragma unroll
    for (int j = 0; j < D; j++) acc[j] = 0.0f;
    const float* arow = magg + (size_t)n * D;
    const float* hrow = hout + (size_t)n * D;
    for (int k = 0; k < D; k++) {
        float a = arow[k];
        const float* w = Wt + k * D;
#pragma unroll
        for (int j = 0; j < D; j++) acc[j] = fmaf(a, w[j], acc[j]);
    }
    for (int k = 0; k < D; k++) {
        float a = hrow[k];
        const float* w = Wt + (D + k) * D;
#pragma unroll
        for (int j = 0; j < D; j++) acc[j] = fmaf(a, w[j], acc[j]);
    }
    float* orow = hout + (size_t)n * D;
#pragma unroll
    for (int j = 0; j < D; j++) orow[j] = acc[j] + bl[j];
}

extern "C" void kernel_launch(void* const* d_in, const int* in_sizes, int n_in,
                              void* d_out, int out_size, void* d_ws, size_t ws_size,
                              hipStream_t stream) {
    const float* x     = (const float*)d_in[0];
    const int*   ei    = (const int*)  d_in[1];
    const float* mask  = (const float*)d_in[2];
    const float* gamma = (const float*)d_in[3];
    const float* beta  = (const float*)d_in[4];
    const float* Wl    = (const float*)d_in[5];
    const float* bl    = (const float*)d_in[6];
    const float* Wr    = (const float*)d_in[7];
    float* out = (float*)d_out;

    int N = in_sizes[0] / D;   // 100000
    int E = in_sizes[1] / 2;   // 600000
    int chunks = (N + SCAN_CHUNK - 1) / SCAN_CHUNK;  // 98

    // ws layout: mean_agg[N*D] | Wt[2*D*D] | hist[N] | offs[N] | cursor[N]
    //            | chunk_sums[128] | sorted_src[E]
    float* magg = (float*)d_ws;
    float* Wt   = magg + (size_t)N * D;
    int* hist   = (int*)(Wt + 2 * D * D);
    int* offs   = hist + N;
    int* cursor = offs + N;
    int* csums  = cursor + N;
    int* ssrc   = csums + 128;

    hipMemsetAsync(hist, 0, (size_t)N * sizeof(int), stream);
    prep_w<<<(2 * D * D + 255) / 256, 256, 0, stream>>>(Wl, Wr, Wt);
    ln_relu_drop<<<(N + 3) / 4, 256, 0, stream>>>(x, mask, gamma, beta, out, N);
    hist_k<<<(E + 255) / 256, 256, 0, stream>>>(ei, hist, E);
    scan1<<<chunks, 256, 0, stream>>>(hist, offs, csums, N);
    scan2<<<1, 128, 0, stream>>>(csums, chunks);
    scan3<<<(N + 255) / 256, 256, 0, stream>>>(offs, csums, cursor, N);
    sort_edges<<<(E + 255) / 256, 256, 0, stream>>>(ei, cursor, ssrc, E);
    aggregate<<<(N + 3) / 4, 256, 0, stream>>>(out, ssrc, offs, hist, magg, N);
    out_gemm<<<(N + 255) / 256, 256, 0, stream>>>(out, magg, Wt, bl, N);
}

// Round 3
// 320.475 us; speedup vs baseline: 4.2614x; 1.4551x over previous
//
#include <hip/hip_runtime.h>

#define LN_EPS 1e-5f
#define D 128
#define SCAN_CHUNK 1024
#define LDSA_STRIDE 264   // bf16 units: 256 + 8 pad -> row stride 528B, <=2-way LDS conflicts (free)

typedef __attribute__((ext_vector_type(4))) float f32x4;
typedef __attribute__((ext_vector_type(8))) short bf16x8;

static __device__ __forceinline__ ushort f2bf(float f) {
    union { float f; unsigned u; } a; a.f = f;
    unsigned r = a.u + 0x7FFF + ((a.u >> 16) & 1);   // RNE
    return (ushort)(r >> 16);
}

// K0: pack B = [Wl^T ; Wr^T] (256k x 128j) into MFMA B-fragment order:
// Bfrag[ks][jb][lane][i]  (ks: k-step of 32, jb: j-block of 16, i: 0..7)
// lane L holds B[k = ks*32 + (L>>4)*8 + i][j = jb*16 + (L&15)].
__global__ void prep_w(const float* __restrict__ Wl,
                       const float* __restrict__ Wr,
                       ushort* __restrict__ Bfrag) {
    int t = blockIdx.x * blockDim.x + threadIdx.x;   // 32768 entries
    if (t >= 8 * 8 * 64 * 8) return;
    int i    = t & 7;
    int lane = (t >> 3) & 63;
    int jb   = (t >> 9) & 7;
    int ks   = t >> 12;
    int k = ks * 32 + (lane >> 4) * 8 + i;
    int j = jb * 16 + (lane & 15);
    float v = (k < D) ? Wl[j * D + k] : Wr[j * D + (k - D)];
    Bfrag[t] = f2bf(v);
}

// K1: LayerNorm + ReLU + dropout-mask. One 64-lane wave per node.
__global__ void ln_relu_drop(const float* __restrict__ x,
                             const float* __restrict__ mask,
                             const float* __restrict__ gamma,
                             const float* __restrict__ beta,
                             float* __restrict__ h, int N) {
    int node = (blockIdx.x * blockDim.x + threadIdx.x) >> 6;
    int lane = threadIdx.x & 63;
    if (node >= N) return;
    float2 v = ((const float2*)(x + (size_t)node * D))[lane];
    float s  = v.x + v.y;
    float ss = v.x * v.x + v.y * v.y;
#pragma unroll
    for (int off = 32; off > 0; off >>= 1) {
        s  += __shfl_xor(s, off);
        ss += __shfl_xor(ss, off);
    }
    float mu  = s * (1.0f / D);
    float var = ss * (1.0f / D) - mu * mu;
    float rs  = rsqrtf(var + LN_EPS);
    float2 g = ((const float2*)gamma)[lane];
    float2 b = ((const float2*)beta)[lane];
    float2 m = ((const float2*)(mask + (size_t)node * D))[lane];
    float2 o;
    o.x = fmaxf((v.x - mu) * rs * g.x + b.x, 0.0f) * m.x;
    o.y = fmaxf((v.y - mu) * rs * g.y + b.y, 0.0f) * m.y;
    ((float2*)(h + (size_t)node * D))[lane] = o;
}

// K2: degree histogram over dst (int atomics).
__global__ void hist_k(const int* __restrict__ ei, int* __restrict__ hist, int E) {
    int e = blockIdx.x * blockDim.x + threadIdx.x;
    if (e >= E) return;
    atomicAdd(&hist[ei[E + e]], 1);
}

// K3a: per-chunk exclusive scan (1024 elems / block of 256 threads).
__global__ void scan1(const int* __restrict__ hist, int* __restrict__ offs,
                      int* __restrict__ chunk_sums, int N) {
    __shared__ int lds[256];
    int base = blockIdx.x * SCAN_CHUNK;
    int t = threadIdx.x;
    int idx0 = base + t * 4;
    int v[4];
#pragma unroll
    for (int i = 0; i < 4; i++) {
        int idx = idx0 + i;
        v[i] = (idx < N) ? hist[idx] : 0;
    }
    lds[t] = v[0] + v[1] + v[2] + v[3];
    __syncthreads();
    for (int off = 1; off < 256; off <<= 1) {
        int add = (t >= off) ? lds[t - off] : 0;
        __syncthreads();
        lds[t] += add;
        __syncthreads();
    }
    int run = (t == 0) ? 0 : lds[t - 1];
    if (t == 255) chunk_sums[blockIdx.x] = lds[255];
#pragma unroll
    for (int i = 0; i < 4; i++) {
        int idx = idx0 + i;
        if (idx < N) offs[idx] = run;
        run += v[i];
    }
}

// K3b: single-block exclusive scan of the chunk sums (C <= 128).
__global__ void scan2(int* __restrict__ chunk_sums, int C) {
    __shared__ int lds[128];
    int t = threadIdx.x;
    lds[t] = (t < C) ? chunk_sums[t] : 0;
    __syncthreads();
    for (int off = 1; off < 128; off <<= 1) {
        int add = (t >= off) ? lds[t - off] : 0;
        __syncthreads();
        lds[t] += add;
        __syncthreads();
    }
    int excl = (t == 0) ? 0 : lds[t - 1];
    if (t < C) chunk_sums[t] = excl;
}

// K3c: add chunk bases; also init the scatter cursor.
__global__ void scan3(int* __restrict__ offs, const int* __restrict__ chunk_sums,
                      int* __restrict__ cursor, int N) {
    int i = blockIdx.x * blockDim.x + threadIdx.x;
    if (i >= N) return;
    int v = offs[i] + chunk_sums[i / SCAN_CHUNK];
    offs[i] = v;
    cursor[i] = v;
}

// K4: bucket edges by dst (counting-sort placement; int atomics only).
__global__ void sort_edges(const int* __restrict__ ei, int* __restrict__ cursor,
                           int* __restrict__ sorted_src, int E) {
    int e = blockIdx.x * blockDim.x + threadIdx.x;
    if (e >= E) return;
    int dst = ei[E + e];
    int pos = atomicAdd(&cursor[dst], 1);
    sorted_src[pos] = ei[e];
}

// K5: segmented mean-aggregate. One wave per node.
__global__ void aggregate(const float* __restrict__ h,
                          const int* __restrict__ sorted_src,
                          const int* __restrict__ offs,
                          const int* __restrict__ hist,
                          float* __restrict__ mean_agg, int N) {
    int node = (blockIdx.x * blockDim.x + threadIdx.x) >> 6;
    int lane = threadIdx.x & 63;
    if (node >= N) return;
    int start = offs[node];
    int deg = hist[node];
    float ax = 0.0f, ay = 0.0f;
    for (int i = 0; i < deg; i++) {
        int src = sorted_src[start + i];
        float2 v = ((const float2*)(h + (size_t)src * D))[lane];
        ax += v.x; ay += v.y;
    }
    float inv = 1.0f / fmaxf((float)deg, 1.0f);
    float2 o; o.x = ax * inv; o.y = ay * inv;
    ((float2*)(mean_agg + (size_t)node * D))[lane] = o;
}

// K6: out = [magg | h] @ B + bias via bf16 MFMA.
// Block = 256 threads = 4 waves; tile = 64 nodes x 128 j.
// A (64x256) staged fp32->bf16 in LDS (padded rows). B fragments pre-packed
// by prep_w; each wave keeps its 2 j-blocks x 8 k-steps of B in VGPRs
// (64 VGPRs), loaded with coalesced dwordx4. In-place on hout (tile rows are
// fully read into LDS before any write).
__global__ void __launch_bounds__(256, 3)
out_gemm_mfma(float* __restrict__ hout,
              const float* __restrict__ magg,
              const ushort* __restrict__ Bfrag,
              const float* __restrict__ bl,
              int N) {
    __shared__ ushort Alds[64 * LDSA_STRIDE];
    int tid  = threadIdx.x;
    int wave = tid >> 6;
    int lane = tid & 63;
    int n0 = blockIdx.x * 64;
    int valid = N - n0; if (valid > 64) valid = 64;

    // B fragments for this wave's 2 j-blocks.
    bf16x8 breg[8][2];
#pragma unroll
    for (int ks = 0; ks < 8; ks++)
#pragma unroll
        for (int jj = 0; jj < 2; jj++) {
            int jb = wave * 2 + jj;
            breg[ks][jj] = *(const bf16x8*)(Bfrag + (size_t)((ks * 8 + jb) * 64 + lane) * 8);
        }

    // Stage A tile: 2048 float4 from magg (k 0..127) + 2048 from h (k 128..255).
    const float4* mg4 = (const float4*)(magg + (size_t)n0 * D);
    const float4* h4  = (const float4*)(hout + (size_t)n0 * D);
#pragma unroll
    for (int r = 0; r < 8; r++) {
        int c = tid + 256 * r;          // 0..2047
        int node = c >> 5;              // 32 float4 per 128-float row
        int k4   = c & 31;
        float4 va = (node < valid) ? mg4[c] : make_float4(0.f, 0.f, 0.f, 0.f);
        float4 vh = (node < valid) ? h4[c]  : make_float4(0.f, 0.f, 0.f, 0.f);
        ushort4 ua; ua.x = f2bf(va.x); ua.y = f2bf(va.y); ua.z = f2bf(va.z); ua.w = f2bf(va.w);
        ushort4 uh; uh.x = f2bf(vh.x); uh.y = f2bf(vh.y); uh.z = f2bf(vh.z); uh.w = f2bf(vh.w);
        *(ushort4*)&Alds[node * LDSA_STRIDE + k4 * 4]       = ua;
        *(ushort4*)&Alds[node * LDSA_STRIDE + 128 + k4 * 4] = uh;
    }
    __syncthreads();

    f32x4 acc[4][2];
#pragma unroll
    for (int nb = 0; nb < 4; nb++)
#pragma unroll
        for (int jj = 0; jj < 2; jj++)
            acc[nb][jj] = (f32x4){0.f, 0.f, 0.f, 0.f};

    int arow = lane & 15;
    int akoff = (lane >> 4) * 8;
#pragma unroll
    for (int ks = 0; ks < 8; ks++) {
#pragma unroll
        for (int nb = 0; nb < 4; nb++) {
            bf16x8 a = *(const bf16x8*)&Alds[(nb * 16 + arow) * LDSA_STRIDE + ks * 32 + akoff];
            acc[nb][0] = __builtin_amdgcn_mfma_f32_16x16x32_bf16(a, breg[ks][0], acc[nb][0], 0, 0, 0);
            acc[nb][1] = __builtin_amdgcn_mfma_f32_16x16x32_bf16(a, breg[ks][1], acc[nb][1], 0, 0, 0);
        }
    }

    // Epilogue: C[row = nb*16 + (lane>>4)*4 + r][col = wave*32 + jj*16 + (lane&15)]
    float bias0 = bl[wave * 32 + (lane & 15)];
    float bias1 = bl[wave * 32 + 16 + (lane & 15)];
    int rbase = (lane >> 4) * 4;
#pragma unroll
    for (int nb = 0; nb < 4; nb++) {
#pragma unroll
        for (int r = 0; r < 4; r++) {
            int row = nb * 16 + rbase + r;
            if (row < valid) {
                float* orow = hout + (size_t)(n0 + row) * D + wave * 32 + (lane & 15);
                orow[0]  = acc[nb][0][r] + bias0;
                orow[16] = acc[nb][1][r] + bias1;
            }
        }
    }
}

extern "C" void kernel_launch(void* const* d_in, const int* in_sizes, int n_in,
                              void* d_out, int out_size, void* d_ws, size_t ws_size,
                              hipStream_t stream) {
    const float* x     = (const float*)d_in[0];
    const int*   ei    = (const int*)  d_in[1];
    const float* mask  = (const float*)d_in[2];
    const float* gamma = (const float*)d_in[3];
    const float* beta  = (const float*)d_in[4];
    const float* Wl    = (const float*)d_in[5];
    const float* bl    = (const float*)d_in[6];
    const float* Wr    = (const float*)d_in[7];
    float* out = (float*)d_out;

    int N = in_sizes[0] / D;   // 100000
    int E = in_sizes[1] / 2;   // 600000
    int chunks = (N + SCAN_CHUNK - 1) / SCAN_CHUNK;  // 98

    // ws layout: mean_agg[N*D] f32 | Bfrag[32768] ushort | hist[N] | offs[N]
    //            | cursor[N] | chunk_sums[128] | sorted_src[E]
    float* magg   = (float*)d_ws;
    ushort* Bfrag = (ushort*)(magg + (size_t)N * D);
    int* hist   = (int*)(Bfrag + 32768);
    int* offs   = hist + N;
    int* cursor = offs + N;
    int* csums  = cursor + N;
    int* ssrc   = csums + 128;

    hipMemsetAsync(hist, 0, (size_t)N * sizeof(int), stream);
    prep_w<<<128, 256, 0, stream>>>(Wl, Wr, Bfrag);
    ln_relu_drop<<<(N + 3) / 4, 256, 0, stream>>>(x, mask, gamma, beta, out, N);
    hist_k<<<(E + 255) / 256, 256, 0, stream>>>(ei, hist, E);
    scan1<<<chunks, 256, 0, stream>>>(hist, offs, csums, N);
    scan2<<<1, 128, 0, stream>>>(csums, chunks);
    scan3<<<(N + 255) / 256, 256, 0, stream>>>(offs, csums, cursor, N);
    sort_edges<<<(E + 255) / 256, 256, 0, stream>>>(ei, cursor, ssrc, E);
    aggregate<<<(N + 3) / 4, 256, 0, stream>>>(out, ssrc, offs, hist, magg, N);
    out_gemm_mfma<<<(N + 63) / 64, 256, 0, stream>>>(out, magg, Bfrag, bl, N);
}